// Round 1
// 539.794 us; speedup vs baseline: 1.0623x; 1.0623x over previous
//
#include <hip/hip_runtime.h>
#include <hip/hip_bf16.h>

#define H 768
#define NH 12
#define DH 64
#define NNODES 2048
#define NEDGES 131072

typedef __bf16 bf16x8 __attribute__((ext_vector_type(8)));
typedef float floatx4 __attribute__((ext_vector_type(4)));

// direct global->LDS DMA, 16B per lane (dest must be wave-uniform base + lane*16)
#define GLOAD_LDS16(gptr, ldsptr)                                                        \
  __builtin_amdgcn_global_load_lds((const __attribute__((address_space(1))) void*)(gptr), \
                                   (__attribute__((address_space(3))) void*)(ldsptr),     \
                                   16, 0, 0)

__device__ __forceinline__ unsigned short f2bf(float x) {
  union { __hip_bfloat16 h; unsigned short u; } cv;
  cv.h = __float2bfloat16(x);
  return cv.u;
}

// ---------------- fp32 -> bf16 conversion (vectorized x4) + denom zero ------
__global__ __launch_bounds__(256)
void convert_kernel(const float* __restrict__ hs,
                    const float* __restrict__ Wq,
                    const float* __restrict__ Wk,
                    const float* __restrict__ Wv,
                    __hip_bfloat16* __restrict__ hsb,
                    __hip_bfloat16* __restrict__ wb,
                    float* __restrict__ denom) {
  int i = blockIdx.x * 256 + threadIdx.x;
  const int n_hs4 = NNODES * H / 4;   // 393216
  const int n_w4  = H * H / 4;        // 147456
  if (i < n_hs4) {
    float4 v = ((const float4*)hs)[i];
    ((ushort4*)hsb)[i] = make_ushort4(f2bf(v.x), f2bf(v.y), f2bf(v.z), f2bf(v.w));
    return;
  }
  int j = i - n_hs4;
  if (j < 3 * n_w4) {
    const float* src = (j < n_w4) ? Wq : (j < 2 * n_w4 ? Wk : Wv);
    float4 v = ((const float4*)src)[j % n_w4];
    ((ushort4*)wb)[j] = make_ushort4(f2bf(v.x), f2bf(v.y), f2bf(v.z), f2bf(v.w));
    return;
  }
  int z = j - 3 * n_w4;
  if (z < NNODES * NH / 4) {          // 6144 float4 = 24576 floats
    ((float4*)denom)[z] = make_float4(0.f, 0.f, 0.f, 0.f);
  }
}

// ---------------- QKV projection GEMM: C = A * W^T + bias -------------------
// A: [2048][768] bf16 row-major (K contiguous)
// W: [768][768] bf16 row-major (rows = output cols, K contiguous) -> gemm_bt
// out: [3][2048][768] fp32
__global__ __launch_bounds__(256)
void qkv_gemm(const __hip_bfloat16* __restrict__ A,
              const __hip_bfloat16* __restrict__ Wb,
              const float* __restrict__ b0,
              const float* __restrict__ b1,
              const float* __restrict__ b2,
              float* __restrict__ out) {
  __shared__ __hip_bfloat16 As[128][32];
  __shared__ __hip_bfloat16 Bs[128][32];

  const int t    = threadIdx.x;
  const int wave = t >> 6;
  const int lane = t & 63;
  const int bm   = blockIdx.x * 128;
  const int bn   = blockIdx.y * 128;
  const int mat  = blockIdx.z;

  const __hip_bfloat16* B = Wb + (size_t)mat * H * H;
  const float* bias = (mat == 0) ? b0 : ((mat == 1) ? b1 : b2);
  float* C = out + (size_t)mat * NNODES * H;

  const int wm = (wave & 1) * 64;
  const int wn = (wave >> 1) * 64;
  const int lr = lane & 15;      // row within 16x16
  const int lq = lane >> 4;      // quad (k-group / acc row group)

  floatx4 acc[4][4] = {};

  const int ar = t >> 2;         // 0..63 (staging row)
  const int ac = (t & 3) * 8;    // 0,8,16,24 (staging k-offset, bf16 elems)
  // LDS flat dest for thread t: ar*32 + ac = t*8 elems = t*16 bytes
  // = wave-uniform base (wave*1024B) + lane*16B  -> valid for global_load_lds
  __hip_bfloat16* AsF = &As[0][0];
  __hip_bfloat16* BsF = &Bs[0][0];

  for (int kt = 0; kt < H; kt += 32) {
    GLOAD_LDS16(A + (size_t)(bm + ar) * H + kt + ac,      AsF + t * 8);
    GLOAD_LDS16(A + (size_t)(bm + 64 + ar) * H + kt + ac, AsF + 64 * 32 + t * 8);
    GLOAD_LDS16(B + (size_t)(bn + ar) * H + kt + ac,      BsF + t * 8);
    GLOAD_LDS16(B + (size_t)(bn + 64 + ar) * H + kt + ac, BsF + 64 * 32 + t * 8);
    __syncthreads();   // drains vmcnt (incl. global_load_lds) before use

    bf16x8 af[4], bfr[4];
#pragma unroll
    for (int i = 0; i < 4; i++)
      af[i] = *(const bf16x8*)&As[wm + i * 16 + lr][lq * 8];
#pragma unroll
    for (int i = 0; i < 4; i++)
      bfr[i] = *(const bf16x8*)&Bs[wn + i * 16 + lr][lq * 8];
#pragma unroll
    for (int mi = 0; mi < 4; mi++)
#pragma unroll
      for (int ni = 0; ni < 4; ni++)
        acc[mi][ni] = __builtin_amdgcn_mfma_f32_16x16x32_bf16(
            af[mi], bfr[ni], acc[mi][ni], 0, 0, 0);
    __syncthreads();
  }

  // epilogue: C/D layout col = lane&15, row = (lane>>4)*4 + reg  [m89-verified]
#pragma unroll
  for (int ni = 0; ni < 4; ni++) {
    int col = bn + wn + ni * 16 + lr;
    float bv = bias[col];
#pragma unroll
    for (int mi = 0; mi < 4; mi++) {
#pragma unroll
      for (int r = 0; r < 4; r++) {
        int row = bm + wm + mi * 16 + lq * 4 + r;
        C[(size_t)row * H + col] = acc[mi][ni][r] + bv;
      }
    }
  }
}

// ---------------- per-edge scores + segment-sum denominator -----------------
// one wave per edge; 16 lanes cooperate per head-dot (3 heads per lane-group)
__global__ __launch_bounds__(256)
void scores_kernel(const float* __restrict__ Q, const float* __restrict__ K,
                   const float* __restrict__ relk,
                   const int* __restrict__ esrc, const int* __restrict__ etgt,
                   const int* __restrict__ epos,
                   float* __restrict__ scores, float* __restrict__ denom) {
  const int wave = threadIdx.x >> 6;
  const int lane = threadIdx.x & 63;
  const int e = blockIdx.x * 4 + wave;
  const int src = esrc[e], tgt = etgt[e], pos = epos[e];
  const int g = lane >> 4;            // lane group 0..3
  const int off = (lane & 15) * 4;    // offset within head

  const float4 r4 = *(const float4*)(relk + pos * DH + off);
  float s[3];
#pragma unroll
  for (int c = 0; c < 3; c++) {
    // chunk c covers heads [4c, 4c+4); this lane's head = 4c + g
    const float4 q4 = *(const float4*)(Q + (size_t)tgt * H + c * 256 + lane * 4);
    const float4 k4 = *(const float4*)(K + (size_t)src * H + c * 256 + lane * 4);
    s[c] = q4.x * (k4.x + r4.x) + q4.y * (k4.y + r4.y) +
           q4.z * (k4.z + r4.z) + q4.w * (k4.w + r4.w);
  }
#pragma unroll
  for (int m = 1; m < 16; m <<= 1) {
    s[0] += __shfl_xor(s[0], m);
    s[1] += __shfl_xor(s[1], m);
    s[2] += __shfl_xor(s[2], m);
  }
  if ((lane & 15) == 0) {
#pragma unroll
    for (int c = 0; c < 3; c++) {
      float sc = __expf(s[c] * 0.125f);   // 1/sqrt(64)
      int h = c * 4 + g;
      scores[(size_t)e * NH + h] = sc;
      atomicAdd(denom + (size_t)tgt * NH + h, sc);
    }
  }
}

// ---------------- per-edge weighted values ----------------------------------
__global__ __launch_bounds__(256)
void weighted_kernel(const float* __restrict__ V, const float* __restrict__ relv,
                     const int* __restrict__ esrc, const int* __restrict__ etgt,
                     const int* __restrict__ epos,
                     const float* __restrict__ scores,
                     const float* __restrict__ denom,
                     float* __restrict__ out) {
  const int wave = threadIdx.x >> 6;
  const int lane = threadIdx.x & 63;
  const int e = blockIdx.x * 4 + wave;
  const int src = esrc[e], tgt = etgt[e], pos = epos[e];
  const int g = lane >> 4;
  const int off = (lane & 15) * 4;

  const float4 r4 = *(const float4*)(relv + pos * DH + off);
#pragma unroll
  for (int c = 0; c < 3; c++) {
    int h = c * 4 + g;
    float a = scores[(size_t)e * NH + h] / denom[(size_t)tgt * NH + h];
    float4 v4 = *(const float4*)(V + (size_t)src * H + c * 256 + lane * 4);
    floatx4 o;
    o.x = (v4.x + r4.x) * a;
    o.y = (v4.y + r4.y) * a;
    o.z = (v4.z + r4.z) * a;
    o.w = (v4.w + r4.w) * a;
    // pure streaming output, never re-read: bypass L2 so the V-row gather
    // (6.3 MB table) stays cache-resident
    __builtin_nontemporal_store(o, (floatx4*)(out + (size_t)e * H + c * 256 + lane * 4));
  }
}

extern "C" void kernel_launch(void* const* d_in, const int* in_sizes, int n_in,
                              void* d_out, int out_size, void* d_ws, size_t ws_size,
                              hipStream_t stream) {
  const float* hs   = (const float*)d_in[0];
  const float* Wq   = (const float*)d_in[1];
  const float* bq   = (const float*)d_in[2];
  const float* Wk   = (const float*)d_in[3];
  const float* bk   = (const float*)d_in[4];
  const float* Wv   = (const float*)d_in[5];
  const float* bv   = (const float*)d_in[6];
  const float* relk = (const float*)d_in[7];
  const float* relv = (const float*)d_in[8];
  const int* esrc   = (const int*)d_in[9];
  const int* etgt   = (const int*)d_in[10];
  // d_in[11] = edges_type (unused by reference)
  const int* epos   = (const int*)d_in[12];
  float* out = (float*)d_out;

  char* ws = (char*)d_ws;
  __hip_bfloat16* hsb = (__hip_bfloat16*)ws;                       // 3,145,728 B
  __hip_bfloat16* wb  = (__hip_bfloat16*)(ws + 3145728);           // 3,538,944 B
  float* qkv    = (float*)(ws + 6684672);                          // 18,874,368 B
  float* scores = (float*)(ws + 25559040);                         // 6,291,456 B
  float* denom  = (float*)(ws + 31850496);                         //    98,304 B

  // 1) convert hs + weights to bf16 (x4 vectorized) + zero denom (fused tail)
  //    threads = 393216 + 442368 + 6144 = 841728 = 3288 * 256
  convert_kernel<<<3288, 256, 0, stream>>>(hs, Wq, Wk, Wv, hsb, wb, denom);

  // 2) QKV projection (bf16 MFMA, fp32 accumulate, global_load_lds staging)
  dim3 grid_gemm(16, 6, 3);
  qkv_gemm<<<grid_gemm, 256, 0, stream>>>(hsb, wb, bq, bk, bv, qkv);

  const float* Qp = qkv;
  const float* Kp = qkv + (size_t)NNODES * H;
  const float* Vp = qkv + (size_t)2 * NNODES * H;

  // 3) per-edge exp-scores + denom scatter-add
  scores_kernel<<<NEDGES / 4, 256, 0, stream>>>(Qp, Kp, relk, esrc, etgt, epos,
                                                scores, denom);

  // 4) per-edge weighted values -> out (nontemporal)
  weighted_kernel<<<NEDGES / 4, 256, 0, stream>>>(Vp, relv, esrc, etgt, epos,
                                                  scores, denom, out);
}